// Round 9
// baseline (706.482 us; speedup 1.0000x reference)
//
#include <hip/hip_runtime.h>
#include <math.h>

#define LSEQ 1024
#define DDIM 256
#define CSTR 144
#define NC 256          // chunks along L (scan + stats), CHUNK=4
#define CHUNK 4
#define GRID 512
#define PR 4            // rows per block in row-phases
#define PI_F 3.14159265358979323846f

// ws float offsets
#define OFF_COEF  0u            // B*L*CSTR      = 294912
#define OFF_V     294912u       // B*L*D         = 524288
#define OFF_PERS  819200u       // B*L*D (tp in place)
#define OFF_GATE  1343488u      // B*L           = 2048
#define OFF_SSUM  1345536u      // B*NC*D        = 131072
#define OFF_SSQ   1476608u      // 131072
#define OFF_RMEAN 1607680u      // 524288
#define OFF_RSTD  2131968u      // 524288
#define OFF_CHP   2656256u      // B*8*L         = 16384
#define OFF_S     2672640u      // B*NC*72*D     = 9437184
#define OFF_CNT   12109824u     // 8 barrier counters (zeroed per call)

// software grid barrier: device-scope atomics (cross-XCD coherent)
__device__ __forceinline__ void gbar(unsigned* cnt, int ph) {
    __syncthreads();                 // drains vmcnt: all block stores in L2
    if (threadIdx.x == 0) {
        __threadfence();             // agent-scope release (L2 writeback)
        __hip_atomic_fetch_add(&cnt[ph], 1u, __ATOMIC_ACQ_REL, __HIP_MEMORY_SCOPE_AGENT);
        while (__hip_atomic_load(&cnt[ph], __ATOMIC_ACQUIRE, __HIP_MEMORY_SCOPE_AGENT) < GRID)
            __builtin_amdgcn_s_sleep(1);
        __threadfence();             // agent-scope acquire
    }
    __syncthreads();
}

__global__ __launch_bounds__(256, 2)
void k_mega(const float* __restrict__ x, const float* __restrict__ kp,
            const float* __restrict__ qp, const float* __restrict__ vp,
            const float* __restrict__ op, const float* __restrict__ lkp,
            const float* __restrict__ pf, const float* __restrict__ bre,
            const float* __restrict__ bim, float* __restrict__ ws,
            float* __restrict__ out) {
    const int bid = blockIdx.x, t = threadIdx.x;
    __shared__ __align__(16) float smem[3456];

    float* coef  = ws + OFF_COEF;
    float* V     = ws + OFF_V;
    float* pers  = ws + OFF_PERS;   // later reused in-place as tp
    float* gate  = ws + OFF_GATE;
    float* Ssum  = ws + OFF_SSUM;
    float* Ssq   = ws + OFF_SSQ;
    float* rmean = ws + OFF_RMEAN;
    float* rstd  = ws + OFF_RSTD;
    float* chp   = ws + OFF_CHP;
    float* S     = ws + OFF_S;
    unsigned* cnt = (unsigned*)(ws + OFF_CNT);

    // ================= P1: phases + V + per-chunk x sums =================
    {
        int r0 = bid * PR;
        float* xs   = smem;          // [4][256]
        float* part = smem + 1024;   // [4][32][2]
        float* phi  = smem + 1280;   // [4][32]
        {
            const float4* src = (const float4*)(x + (size_t)r0 * DDIM);
            ((float4*)xs)[t] = src[t];
        }
        __syncthreads();
        {   // stats1: this block's 4 rows ARE chunk (b=bid>>8, c=bid&255)
            float v0 = xs[t], v1 = xs[256 + t], v2 = xs[512 + t], v3 = xs[768 + t];
            Ssum[bid * DDIM + t] = v0 + v1 + v2 + v3;
            Ssq [bid * DDIM + t] = v0*v0 + v1*v1 + v2*v2 + v3*v3;
        }
        {   // 4 rows x 32 dots x 2 splits
            int r = t >> 6, rem = t & 63, j5 = rem >> 1, s = rem & 1;
            const float* W = (j5 < 16) ? kp : qp;
            int j = j5 & 15, i0 = s * 128;
            const float* xr = xs + r * 256;
            float acc = 0.f;
            #pragma unroll 8
            for (int i = 0; i < 128; ++i) acc += xr[i0 + i] * W[(i0 + i) * 16 + j];
            part[(r * 32 + j5) * 2 + s] = acc;
        }
        __syncthreads();
        if (t < 128) {
            int r = t >> 5, j5 = t & 31;
            float ph = tanhf(part[(r*32+j5)*2] + part[(r*32+j5)*2 + 1]) * PI_F;
            phi[r * 32 + j5] = ph;
            float s, c; sincosf(ph, &s, &c);   // SIN FIRST
            int j = j5 & 15;
            float* crow = coef + (size_t)(r0 + r) * CSTR;
            if (j5 < 16) { crow[j] = c;               crow[36 + j] = s; }
            else         { crow[72 + j] = 0.025f * c; crow[108 + j] = 0.025f * s; }
        }
        __syncthreads();
        if (t < PR * 8) {
            int r = t >> 3, k = t & 7, p = k & 3;
            const float* p4 = phi + r * 32 + ((k < 4) ? 0 : 16);
            float sum = p4[p] + p4[4 + p] + p4[8 + p] + p4[12 + p];
            float s, c; sincosf(sum, &s, &c);
            float* crow = coef + (size_t)(r0 + r) * CSTR;
            if (k < 4) { crow[16 + p] = c;        crow[52 + p] = s; }
            else       { crow[88 + p] = 0.1f * c; crow[124 + p] = 0.1f * s; }
        }
        if (t >= 64 && t < 64 + PR * 16) {
            int u = t - 64, r = u >> 4, pl = u & 15;
            int l = (r0 + r) & (LSEQ - 1);
            float a = (((float)l * pf[pl]) * 2.0f) * PI_F;
            float s, c; sincosf(a, &s, &c);
            float* crow = coef + (size_t)(r0 + r) * CSTR;
            crow[20 + pl] = c;        crow[56 + pl] = s;
            crow[92 + pl] = 0.5f * c; crow[128 + pl] = 0.5f * s;
        }
        // V = x @ value_proj (4 rows per thread-column)
        float a0 = 0.f, a1 = 0.f, a2 = 0.f, a3 = 0.f;
        const float4* x40 = (const float4*)xs;
        const float4* x41 = (const float4*)(xs + 256);
        const float4* x42 = (const float4*)(xs + 512);
        const float4* x43 = (const float4*)(xs + 768);
        #pragma unroll 4
        for (int i4 = 0; i4 < 64; ++i4) {
            float w0 = vp[(4*i4+0) * DDIM + t];
            float w1 = vp[(4*i4+1) * DDIM + t];
            float w2 = vp[(4*i4+2) * DDIM + t];
            float w3 = vp[(4*i4+3) * DDIM + t];
            float4 v;
            v = x40[i4]; a0 += v.x*w0 + v.y*w1 + v.z*w2 + v.w*w3;
            v = x41[i4]; a1 += v.x*w0 + v.y*w1 + v.z*w2 + v.w*w3;
            v = x42[i4]; a2 += v.x*w0 + v.y*w1 + v.z*w2 + v.w*w3;
            v = x43[i4]; a3 += v.x*w0 + v.y*w1 + v.z*w2 + v.w*w3;
        }
        V[(size_t)(r0+0)*DDIM + t] = a0;
        V[(size_t)(r0+1)*DDIM + t] = a1;
        V[(size_t)(r0+2)*DDIM + t] = a2;
        V[(size_t)(r0+3)*DDIM + t] = a3;
    }
    gbar(cnt, 0);

    // ================= P2: gate channel scans (bid<16) + running stats =================
    {
        if (bid < 16) {   // one block per (b, channel): exclusive scan of 1024
            int b = bid >> 3, ch = bid & 7;
            float* sm = smem;   // [256]
            int coff = (ch < 4) ? (16 + ch) : (48 + ch);
            const float* cb = coef + (size_t)b * LSEQ * CSTR + coff;
            float v0 = cb[(size_t)(t*4+0) * CSTR];
            float v1 = cb[(size_t)(t*4+1) * CSTR];
            float v2 = cb[(size_t)(t*4+2) * CSTR];
            float v3 = cb[(size_t)(t*4+3) * CSTR];
            sm[t] = v0 + v1 + v2 + v3;
            __syncthreads();
            for (int ofs = 1; ofs < 256; ofs <<= 1) {   // Hillis-Steele inclusive
                float add = (t >= ofs) ? sm[t - ofs] : 0.f;
                __syncthreads();
                sm[t] += add;
                __syncthreads();
            }
            float run = (t == 0) ? 0.f : sm[t - 1];
            float* cp = chp + (size_t)(b * 8 + ch) * LSEQ;
            cp[t*4+0] = run; run += v0;
            cp[t*4+1] = run; run += v1;
            cp[t*4+2] = run; run += v2;
            cp[t*4+3] = run; run += v3;
        }
        {   // stats2: b = bid>>8, c = bid&255, 4-row replay
            int b = bid >> 8, c = bid & 255;
            float cs = 0.f, css = 0.f;
            for (int cc = 0; cc < c; ++cc) {
                cs  += Ssum[(b * NC + cc) * DDIM + t];
                css += Ssq [(b * NC + cc) * DDIM + t];
            }
            const float* xr = x     + ((size_t)(b * LSEQ + c * CHUNK)) * DDIM + t;
            float* mr       = rmean + ((size_t)(b * LSEQ + c * CHUNK)) * DDIM + t;
            float* sr       = rstd  + ((size_t)(b * LSEQ + c * CHUNK)) * DDIM + t;
            #pragma unroll
            for (int i = 0; i < CHUNK; ++i) {
                float v = xr[(size_t)i * DDIM];
                cs += v; css += v * v;
                int l = c * CHUNK + i;
                float inv = 1.0f / (float)(l + 1);
                float m = cs * inv;
                float var = css * inv - m * m;
                mr[(size_t)i * DDIM] = m;
                sr[(size_t)i * DDIM] = sqrtf(fmaxf(var, 1e-8f));
            }
        }
    }
    gbar(cnt, 1);

    // ================= P3: LTM (all) + gate eval (bid<8) =================
    {
        int r0 = bid * PR;
        float* ins  = smem;          // [4][768]
        float* part = smem + 3072;   // [4][16][4]
        float* csn  = smem + 3328;   // [4][2][16]
        #pragma unroll
        for (int r = 0; r < PR; ++r) {
            size_t row = (size_t)(r0 + r) * DDIM;
            ins[r*768 + t]       = x[row + t];
            ins[r*768 + 256 + t] = rmean[row + t];
            ins[r*768 + 512 + t] = rstd[row + t];
        }
        __syncthreads();
        {   // 4 rows x 16 outs x 4 splits of 192
            int r = t >> 6, rem = t & 63, j = rem >> 2, h = rem & 3;
            int i0 = h * 192;
            const float* ir = ins + r * 768;
            float acc = 0.f;
            #pragma unroll 8
            for (int i = 0; i < 192; ++i) acc += ir[i0 + i] * lkp[(i0 + i) * 16 + j];
            part[(r * 16 + j) * 4 + h] = acc;
        }
        __syncthreads();
        if (t < 64) {
            int r = t >> 4, j = t & 15;
            const float* pp = part + (r * 16 + j) * 4;
            float th = tanhf(pp[0] + pp[1] + pp[2] + pp[3]) * PI_F;
            float s, c; sincosf(th, &s, &c);   // SIN FIRST
            csn[r * 32 + j] = c; csn[r * 32 + 16 + j] = s;
        }
        __syncthreads();
        float a0 = 0.f, a1 = 0.f, a2 = 0.f, a3 = 0.f;
        #pragma unroll
        for (int pl = 0; pl < 16; ++pl) {
            float br = bre[pl * DDIM + t], bi = bim[pl * DDIM + t];
            a0 += br * csn[pl]      + bi * csn[16 + pl];
            a1 += br * csn[32 + pl] + bi * csn[48 + pl];
            a2 += br * csn[64 + pl] + bi * csn[80 + pl];
            a3 += br * csn[96 + pl] + bi * csn[112 + pl];
        }
        pers[(size_t)(r0+0)*DDIM + t] = a0;
        pers[(size_t)(r0+1)*DDIM + t] = a1;
        pers[(size_t)(r0+2)*DDIM + t] = a2;
        pers[(size_t)(r0+3)*DDIM + t] = a3;

        if (bid < 8) {   // gate eval: b = bid>>2, l = (bid&3)*256 + t
            int b = bid >> 2, l = (bid & 3) * 256 + t;
            float m = 0.f;
            #pragma unroll
            for (int p = 0; p < 4; ++p) {
                float re = chp[(size_t)(b * 8 + p) * LSEQ + l];
                float im = chp[(size_t)(b * 8 + 4 + p) * LSEQ + l];
                m += sqrtf(re * re + im * im);
            }
            m *= 0.25f;
            float nr = m / sqrtf(fmaxf((float)l, 1.0f));
            float sup = 0.5f * (1.0f - tanhf(5.0f * (nr - 0.3f)));
            gate[b * LSEQ + l] = 1.0f / (1.0f + expf(-5.0f * (sup - 0.5f)));
        }
    }
    gbar(cnt, 2);

    // ================= P4: per-chunk plane sums =================
    {
        int b = bid >> 8, c = bid & 255;
        const float* cr0 = coef + ((size_t)(b * LSEQ + c * CHUNK)) * CSTR;
        const float* gt  = gate + b * LSEQ + c * CHUNK;
        float vbuf[CHUNK];
        #pragma unroll
        for (int l = 0; l < CHUNK; ++l)
            vbuf[l] = V[((size_t)(b * LSEQ + c * CHUNK + l)) * DDIM + t];
        float sre[36], sim[36];
        #pragma unroll
        for (int i = 0; i < 36; ++i) { sre[i] = 0.f; sim[i] = 0.f; }
        #pragma unroll
        for (int l = 0; l < CHUNK; ++l) {
            const float* cr = cr0 + l * CSTR;   // block-uniform -> s_load
            float g = gt[l], v = vbuf[l], vg = v * g;
            #pragma unroll
            for (int q = 0; q < 9; ++q) {
                float val = (q <= 4) ? vg : v;
                #pragma unroll
                for (int j = 0; j < 4; ++j) {
                    sre[4*q+j] += cr[4*q+j] * val;
                    sim[4*q+j] += cr[36 + 4*q+j] * val;
                }
            }
        }
        size_t base = ((size_t)(b * NC + c) * 72) * DDIM + t;
        #pragma unroll
        for (int i = 0; i < 36; ++i) {
            S[base + (size_t)i * DDIM] = sre[i];
            S[base + (size_t)(36 + i) * DDIM] = sim[i];
        }
    }
    gbar(cnt, 3);

    // ================= P5: exclusive prefix over chunks (bid<144) =================
    {
        if (bid < 144) {
            int b = bid / 72, q = bid % 72;
            float acc = 0.f;
            for (int batch = 0; batch < NC / 32; ++batch) {
                float r[32];
                #pragma unroll
                for (int i = 0; i < 32; ++i)
                    r[i] = S[((size_t)(b * NC + batch * 32 + i) * 72 + q) * DDIM + t];
                #pragma unroll
                for (int i = 0; i < 32; ++i) { float tmp = r[i]; r[i] = acc; acc += tmp; }
                #pragma unroll
                for (int i = 0; i < 32; ++i)
                    S[((size_t)(b * NC + batch * 32 + i) * 72 + q) * DDIM + t] = r[i];
            }
        }
    }
    gbar(cnt, 4);

    // ================= P6: within-chunk scan + retrieval (+0.125*pers in place) =================
    {
        int b = bid >> 8, c = bid & 255;
        const float* cr0 = coef + ((size_t)(b * LSEQ + c * CHUNK)) * CSTR;
        const float* gt  = gate + b * LSEQ + c * CHUNK;
        float* tp = pers;
        float vbuf[CHUNK], tpb[CHUNK];
        #pragma unroll
        for (int l = 0; l < CHUNK; ++l) {
            size_t idx = ((size_t)(b * LSEQ + c * CHUNK + l)) * DDIM + t;
            vbuf[l] = V[idx];
            tpb[l]  = tp[idx];
        }
        float sre[36], sim[36];
        size_t base = ((size_t)(b * NC + c) * 72) * DDIM + t;
        #pragma unroll
        for (int i = 0; i < 36; ++i) {
            sre[i] = S[base + (size_t)i * DDIM];
            sim[i] = S[base + (size_t)(36 + i) * DDIM];
        }
        #pragma unroll
        for (int l = 0; l < CHUNK; ++l) {
            const float* cr = cr0 + l * CSTR;
            float g = gt[l], v = vbuf[l], vg = v * g;
            float rx = 0.f, ry = 0.f, rz = 0.f, rw = 0.f;
            #pragma unroll
            for (int q = 0; q < 9; ++q) {
                float val = (q <= 4) ? vg : v;
                sre[4*q+0] += cr[4*q+0] * val; rx += cr[72+4*q+0] * sre[4*q+0];
                sre[4*q+1] += cr[4*q+1] * val; ry += cr[72+4*q+1] * sre[4*q+1];
                sre[4*q+2] += cr[4*q+2] * val; rz += cr[72+4*q+2] * sre[4*q+2];
                sre[4*q+3] += cr[4*q+3] * val; rw += cr[72+4*q+3] * sre[4*q+3];
                sim[4*q+0] += cr[36+4*q+0] * val; rx += cr[108+4*q+0] * sim[4*q+0];
                sim[4*q+1] += cr[36+4*q+1] * val; ry += cr[108+4*q+1] * sim[4*q+1];
                sim[4*q+2] += cr[36+4*q+2] * val; rz += cr[108+4*q+2] * sim[4*q+2];
                sim[4*q+3] += cr[36+4*q+3] * val; rw += cr[108+4*q+3] * sim[4*q+3];
            }
            size_t oidx = ((size_t)(b * LSEQ + c * CHUNK + l)) * DDIM + t;
            tp[oidx] = ((rx + ry) + (rz + rw)) + 0.125f * tpb[l];
        }
    }
    gbar(cnt, 5);

    // ================= P7: epilogue (total/norm) @ out_proj + x =================
    {
        int r0 = bid * PR;
        float* ts = smem;   // [4][256]
        #pragma unroll
        for (int r = 0; r < PR; ++r) {
            int l = (r0 + r) & (LSEQ - 1);
            float invn = 1.0f / (2.0f * sqrtf((float)(l + 1)));
            ts[r * 256 + t] = pers[(size_t)(r0 + r) * DDIM + t] * invn;
        }
        __syncthreads();
        float a0 = 0.f, a1 = 0.f, a2 = 0.f, a3 = 0.f;
        const float4* t40 = (const float4*)ts;
        const float4* t41 = (const float4*)(ts + 256);
        const float4* t42 = (const float4*)(ts + 512);
        const float4* t43 = (const float4*)(ts + 768);
        #pragma unroll 4
        for (int i4 = 0; i4 < 64; ++i4) {
            float w0 = op[(4*i4+0) * DDIM + t];
            float w1 = op[(4*i4+1) * DDIM + t];
            float w2 = op[(4*i4+2) * DDIM + t];
            float w3 = op[(4*i4+3) * DDIM + t];
            float4 v;
            v = t40[i4]; a0 += v.x*w0 + v.y*w1 + v.z*w2 + v.w*w3;
            v = t41[i4]; a1 += v.x*w0 + v.y*w1 + v.z*w2 + v.w*w3;
            v = t42[i4]; a2 += v.x*w0 + v.y*w1 + v.z*w2 + v.w*w3;
            v = t43[i4]; a3 += v.x*w0 + v.y*w1 + v.z*w2 + v.w*w3;
        }
        out[(size_t)(r0+0)*DDIM + t] = x[(size_t)(r0+0)*DDIM + t] + a0;
        out[(size_t)(r0+1)*DDIM + t] = x[(size_t)(r0+1)*DDIM + t] + a1;
        out[(size_t)(r0+2)*DDIM + t] = x[(size_t)(r0+2)*DDIM + t] + a2;
        out[(size_t)(r0+3)*DDIM + t] = x[(size_t)(r0+3)*DDIM + t] + a3;
    }
}

extern "C" void kernel_launch(void* const* d_in, const int* in_sizes, int n_in,
                              void* d_out, int out_size, void* d_ws, size_t ws_size,
                              hipStream_t stream) {
    const float* x   = (const float*)d_in[0];
    const float* kp  = (const float*)d_in[1];
    const float* qp  = (const float*)d_in[2];
    const float* vp  = (const float*)d_in[3];
    const float* op  = (const float*)d_in[4];
    const float* lkp = (const float*)d_in[5];
    const float* pf  = (const float*)d_in[7];
    const float* bre = (const float*)d_in[10];
    const float* bim = (const float*)d_in[11];
    float* ws  = (float*)d_ws;
    float* out = (float*)d_out;

    // zero the 6 barrier counters (graph-capture-safe async memset)
    hipMemsetAsync((char*)d_ws + (size_t)OFF_CNT * sizeof(float), 0, 64, stream);

    k_mega<<<dim3(GRID), dim3(256), 0, stream>>>(x, kp, qp, vp, op, lkp, pf,
                                                 bre, bim, ws, out);
}

// Round 10
// 109.036 us; speedup vs baseline: 6.4794x; 6.4794x over previous
//
#include <hip/hip_runtime.h>
#include <math.h>

#define LSEQ 1024
#define DDIM 256
#define NC 64          // chunks along L (scan pipeline)
#define CHUNK 16
#define NCS 16         // chunks along L (stats)
#define CHS 64
#define CSTR 144
#define ROWS 2
#define PI_F 3.14159265358979323846f

// coef row layout (per b,l), 36 planes = 16 bank + 4 joint + 16 pos:
// [0:36) Kre  [36:72) Kim  [72:108) Qre  [108:144) Qim
// (Q weights folded: bank 0.025, joint 0.1, pos 0.5. Gate applied via chp inline.)

__device__ __forceinline__ float gate_of(const float* __restrict__ chp, int b, int l) {
    float m = 0.f;
    #pragma unroll
    for (int p = 0; p < 4; ++p) {
        float re = chp[(size_t)(b * 8 + p) * LSEQ + l];
        float im = chp[(size_t)(b * 8 + 4 + p) * LSEQ + l];
        m += sqrtf(re * re + im * im);
    }
    m *= 0.25f;
    float nr = m / sqrtf(fmaxf((float)l, 1.0f));
    float sup = 0.5f * (1.0f - tanhf(5.0f * (nr - 0.3f)));
    return 1.0f / (1.0f + expf(-5.0f * (sup - 0.5f)));
}

// ---------------- A: phases+V (bid<1024) | stats1 (bid>=1024, 32 blocks) ----------------
__global__ void kA(const float* __restrict__ x, const float* __restrict__ kp,
                   const float* __restrict__ qp, const float* __restrict__ vp,
                   const float* __restrict__ pos_freqs, float* __restrict__ coef,
                   float* __restrict__ V, float* __restrict__ Ssum,
                   float* __restrict__ Ssq) {
    int bid = blockIdx.x, t = threadIdx.x;
    __shared__ __align__(16) float xs[ROWS][DDIM];
    __shared__ float part[ROWS][32][5];
    __shared__ float phi[ROWS][32];
    if (bid < 1024) {
        int r0 = bid * ROWS;
        {
            const float4* src = (const float4*)(x + (size_t)r0 * DDIM);
            float4* dst = (float4*)&xs[0][0];
            if (t < ROWS * DDIM / 4) dst[t] = src[t];
        }
        __syncthreads();
        {   // 64 phase-dots x 4-way i-split = 256 threads
            int r = t >> 7, rem = t & 127, j5 = rem >> 2, s = rem & 3;
            const float* W = (j5 < 16) ? kp : qp;
            int j = j5 & 15;
            int i0 = s * 64;
            float acc = 0.f;
            #pragma unroll 8
            for (int i = 0; i < 64; ++i) acc += xs[r][i0 + i] * W[(i0 + i) * 16 + j];
            part[r][j5][s] = acc;
        }
        __syncthreads();
        if (t < ROWS * 32) {
            int r = t >> 5, j5 = t & 31;
            float ph = tanhf(part[r][j5][0] + part[r][j5][1]
                           + part[r][j5][2] + part[r][j5][3]) * PI_F;
            phi[r][j5] = ph;
            float s, c; sincosf(ph, &s, &c);   // SIN FIRST
            int j = j5 & 15;
            float* crow = coef + (size_t)(r0 + r) * CSTR;
            if (j5 < 16) { crow[j] = c;               crow[36 + j] = s; }
            else         { crow[72 + j] = 0.025f * c; crow[108 + j] = 0.025f * s; }
        }
        __syncthreads();
        if (t < ROWS * 8) {
            int r = t >> 3, k = t & 7, p = k & 3;
            const float* p4 = phi[r] + ((k < 4) ? 0 : 16);
            float sum = p4[p] + p4[4 + p] + p4[8 + p] + p4[12 + p];
            float s, c; sincosf(sum, &s, &c);
            float* crow = coef + (size_t)(r0 + r) * CSTR;
            if (k < 4) { crow[16 + p] = c;        crow[52 + p] = s; }
            else       { crow[88 + p] = 0.1f * c; crow[124 + p] = 0.1f * s; }
        }
        if (t >= 64 && t < 64 + ROWS * 16) {
            int u = t - 64, r = u >> 4, pl = u & 15;
            int l = (r0 + r) & (LSEQ - 1);
            float a = (((float)l * pos_freqs[pl]) * 2.0f) * PI_F;
            float s, c; sincosf(a, &s, &c);
            float* crow = coef + (size_t)(r0 + r) * CSTR;
            crow[20 + pl] = c;        crow[56 + pl] = s;
            crow[92 + pl] = 0.5f * c; crow[128 + pl] = 0.5f * s;
        }
        float a0 = 0.f, a1 = 0.f;
        const float4* x40 = (const float4*)&xs[0][0];
        const float4* x41 = (const float4*)&xs[1][0];
        #pragma unroll 4
        for (int i4 = 0; i4 < DDIM / 4; ++i4) {
            float4 v0 = x40[i4], v1 = x41[i4];
            float w0 = vp[(4*i4+0) * DDIM + t];
            float w1 = vp[(4*i4+1) * DDIM + t];
            float w2 = vp[(4*i4+2) * DDIM + t];
            float w3 = vp[(4*i4+3) * DDIM + t];
            a0 += v0.x * w0 + v0.y * w1 + v0.z * w2 + v0.w * w3;
            a1 += v1.x * w0 + v1.y * w1 + v1.z * w2 + v1.w * w3;
        }
        V[(size_t)(r0 + 0) * DDIM + t] = a0;
        V[(size_t)(r0 + 1) * DDIM + t] = a1;
    } else {   // stats1: 32 blocks, (b,c), d=t
        int bid2 = bid - 1024;
        int b = bid2 >> 4, c = bid2 & 15;
        float s1 = 0.f, s2 = 0.f;
        for (int l = c * CHS; l < c * CHS + CHS; ++l) {
            float v = x[((size_t)(b * LSEQ + l)) * DDIM + t];
            s1 += v; s2 += v * v;
        }
        Ssum[(b * NCS + c) * DDIM + t] = s1;
        Ssq [(b * NCS + c) * DDIM + t] = s2;
    }
}

// ---------------- B: joint-key Hillis scans (bid<16) | stats2 (32 blocks) ----------------
__global__ void kB(const float* __restrict__ x, const float* __restrict__ coef,
                   float* __restrict__ chp, const float* __restrict__ Ssum,
                   const float* __restrict__ Ssq, float* __restrict__ rmean,
                   float* __restrict__ rstd) {
    int bid = blockIdx.x, t = threadIdx.x;
    __shared__ float sm[256];
    if (bid < 16) {   // one block per (b, channel): exclusive scan of 1024
        int b = bid >> 3, ch = bid & 7;
        int coff = (ch < 4) ? (16 + ch) : (48 + ch);
        const float* cb = coef + (size_t)b * LSEQ * CSTR + coff;
        float v0 = cb[(size_t)(t*4+0) * CSTR];
        float v1 = cb[(size_t)(t*4+1) * CSTR];
        float v2 = cb[(size_t)(t*4+2) * CSTR];
        float v3 = cb[(size_t)(t*4+3) * CSTR];
        sm[t] = v0 + v1 + v2 + v3;
        __syncthreads();
        for (int ofs = 1; ofs < 256; ofs <<= 1) {   // Hillis-Steele inclusive
            float add = (t >= ofs) ? sm[t - ofs] : 0.f;
            __syncthreads();
            sm[t] += add;
            __syncthreads();
        }
        float run = (t == 0) ? 0.f : sm[t - 1];
        float* cp = chp + (size_t)(b * 8 + ch) * LSEQ;
        cp[t*4+0] = run; run += v0;
        cp[t*4+1] = run; run += v1;
        cp[t*4+2] = run; run += v2;
        cp[t*4+3] = run; run += v3;
    } else {   // stats2: (b,c), d=t, 64-row replay
        int bid2 = bid - 16;
        int b = bid2 >> 4, c = bid2 & 15;
        float cs = 0.f, css = 0.f;
        for (int cc = 0; cc < c; ++cc) {
            cs  += Ssum[(b * NCS + cc) * DDIM + t];
            css += Ssq [(b * NCS + cc) * DDIM + t];
        }
        for (int l = c * CHS; l < c * CHS + CHS; ++l) {
            size_t idx = ((size_t)(b * LSEQ + l)) * DDIM + t;
            float v = x[idx];
            cs += v; css += v * v;
            float inv = 1.0f / (float)(l + 1);
            float m = cs * inv;
            float var = css * inv - m * m;
            rmean[idx] = m;
            rstd[idx] = sqrtf(fmaxf(var, 1e-8f));
        }
    }
}

// ---------------- C: LTM (bid<1024) | chunksum w/ inline gate (128 blocks) ----------------
__global__ void kC(const float* __restrict__ x, const float* __restrict__ rmean,
                   const float* __restrict__ rstd, const float* __restrict__ lkp,
                   const float* __restrict__ bre, const float* __restrict__ bim,
                   float* __restrict__ pers, const float* __restrict__ coef,
                   const float* __restrict__ V, const float* __restrict__ chp,
                   float* __restrict__ S) {
    int bid = blockIdx.x, t = threadIdx.x;
    __shared__ float ins[ROWS][768];
    __shared__ float part[ROWS][16][9];
    __shared__ float csn[ROWS][2][16];
    if (bid < 1024) {
        int r0 = bid * ROWS;
        {
            size_t row0 = (size_t)r0 * DDIM, row1 = (size_t)(r0 + 1) * DDIM;
            ins[0][t]       = x[row0 + t];
            ins[0][256 + t] = rmean[row0 + t];
            ins[0][512 + t] = rstd[row0 + t];
            ins[1][t]       = x[row1 + t];
            ins[1][256 + t] = rmean[row1 + t];
            ins[1][512 + t] = rstd[row1 + t];
        }
        __syncthreads();
        {   // 32 dots x 8-way split of 96
            int r = t >> 7, rem = t & 127, j = rem >> 3, h = rem & 7;
            int i0 = h * 96;
            float acc = 0.f;
            #pragma unroll 8
            for (int i = 0; i < 96; ++i) acc += ins[r][i0 + i] * lkp[(i0 + i) * 16 + j];
            part[r][j][h] = acc;
        }
        __syncthreads();
        if (t < ROWS * 16) {
            int r = t >> 4, j = t & 15;
            float acc = 0.f;
            #pragma unroll
            for (int h = 0; h < 8; ++h) acc += part[r][j][h];
            float th = tanhf(acc) * PI_F;
            float s, c; sincosf(th, &s, &c);   // SIN FIRST
            csn[r][0][j] = c; csn[r][1][j] = s;
        }
        __syncthreads();
        float a0 = 0.f, a1 = 0.f;
        #pragma unroll
        for (int pl = 0; pl < 16; ++pl) {
            float br = bre[pl * DDIM + t], bi = bim[pl * DDIM + t];
            a0 += br * csn[0][0][pl] + bi * csn[0][1][pl];
            a1 += br * csn[1][0][pl] + bi * csn[1][1][pl];
        }
        pers[(size_t)(bid * ROWS + 0) * DDIM + t] = a0;
        pers[(size_t)(bid * ROWS + 1) * DDIM + t] = a1;
    } else {   // chunksum: (b,c), d=t
        int bid2 = bid - 1024;
        int b = bid2 >> 6, c = bid2 & 63;
        float* gl = &ins[0][0];   // reuse LDS
        if (t < CHUNK) gl[t] = gate_of(chp, b, c * CHUNK + t);
        __syncthreads();
        const float* cr0 = coef + ((size_t)(b * LSEQ + c * CHUNK)) * CSTR;
        float vbuf[CHUNK];
        #pragma unroll
        for (int l = 0; l < CHUNK; ++l)
            vbuf[l] = V[((size_t)(b * LSEQ + c * CHUNK + l)) * DDIM + t];
        float sre[36], sim[36];
        #pragma unroll
        for (int i = 0; i < 36; ++i) { sre[i] = 0.f; sim[i] = 0.f; }
        #pragma unroll
        for (int l = 0; l < CHUNK; ++l) {
            const float* cr = cr0 + l * CSTR;   // block-uniform -> s_load
            float g = gl[l], v = vbuf[l], vg = v * g;
            #pragma unroll
            for (int q = 0; q < 9; ++q) {
                float val = (q <= 4) ? vg : v;
                #pragma unroll
                for (int j = 0; j < 4; ++j) {
                    sre[4*q+j] += cr[4*q+j] * val;
                    sim[4*q+j] += cr[36 + 4*q+j] * val;
                }
            }
        }
        size_t base = ((size_t)(b * NC + c) * 72) * DDIM + t;
        #pragma unroll
        for (int i = 0; i < 36; ++i) {
            S[base + (size_t)i * DDIM] = sre[i];
            S[base + (size_t)(36 + i) * DDIM] = sim[i];
        }
    }
}

// ---------------- D: exclusive prefix over chunks ----------------
__global__ void kD(float* __restrict__ S) {
    int bid = blockIdx.x, t = threadIdx.x;
    int b = bid / 72, q = bid % 72;
    float acc = 0.f;
    for (int batch = 0; batch < NC / 32; ++batch) {
        float r[32];
        #pragma unroll
        for (int i = 0; i < 32; ++i)
            r[i] = S[((size_t)(b * NC + batch * 32 + i) * 72 + q) * DDIM + t];
        #pragma unroll
        for (int i = 0; i < 32; ++i) { float tmp = r[i]; r[i] = acc; acc += tmp; }
        #pragma unroll
        for (int i = 0; i < 32; ++i)
            S[((size_t)(b * NC + batch * 32 + i) * 72 + q) * DDIM + t] = r[i];
    }
}

// ---------------- E: within-chunk scan + retrieval (+0.125*pers in place) ----------------
__global__ void kE(const float* __restrict__ coef, const float* __restrict__ V,
                   const float* __restrict__ chp, const float* __restrict__ S,
                   float* __restrict__ tp) {
    int bid = blockIdx.x, t = threadIdx.x;
    int b = bid >> 6, c = bid & 63;
    __shared__ float gl[CHUNK];
    if (t < CHUNK) gl[t] = gate_of(chp, b, c * CHUNK + t);
    __syncthreads();
    const float* cr0 = coef + ((size_t)(b * LSEQ + c * CHUNK)) * CSTR;
    float vbuf[CHUNK], tpb[CHUNK];
    #pragma unroll
    for (int l = 0; l < CHUNK; ++l) {
        size_t idx = ((size_t)(b * LSEQ + c * CHUNK + l)) * DDIM + t;
        vbuf[l] = V[idx];
        tpb[l]  = tp[idx];
    }
    float sre[36], sim[36];
    size_t base = ((size_t)(b * NC + c) * 72) * DDIM + t;
    #pragma unroll
    for (int i = 0; i < 36; ++i) {
        sre[i] = S[base + (size_t)i * DDIM];
        sim[i] = S[base + (size_t)(36 + i) * DDIM];
    }
    #pragma unroll
    for (int l = 0; l < CHUNK; ++l) {
        const float* cr = cr0 + l * CSTR;   // block-uniform -> s_load
        float g = gl[l], v = vbuf[l], vg = v * g;
        float rx = 0.f, ry = 0.f, rz = 0.f, rw = 0.f;
        #pragma unroll
        for (int q = 0; q < 9; ++q) {
            float val = (q <= 4) ? vg : v;
            sre[4*q+0] += cr[4*q+0] * val; rx += cr[72+4*q+0] * sre[4*q+0];
            sre[4*q+1] += cr[4*q+1] * val; ry += cr[72+4*q+1] * sre[4*q+1];
            sre[4*q+2] += cr[4*q+2] * val; rz += cr[72+4*q+2] * sre[4*q+2];
            sre[4*q+3] += cr[4*q+3] * val; rw += cr[72+4*q+3] * sre[4*q+3];
            sim[4*q+0] += cr[36+4*q+0] * val; rx += cr[108+4*q+0] * sim[4*q+0];
            sim[4*q+1] += cr[36+4*q+1] * val; ry += cr[108+4*q+1] * sim[4*q+1];
            sim[4*q+2] += cr[36+4*q+2] * val; rz += cr[108+4*q+2] * sim[4*q+2];
            sim[4*q+3] += cr[36+4*q+3] * val; rw += cr[108+4*q+3] * sim[4*q+3];
        }
        size_t oidx = ((size_t)(b * LSEQ + c * CHUNK + l)) * DDIM + t;
        tp[oidx] = ((rx + ry) + (rz + rw)) + 0.125f * tpb[l];  // tp aliases pers
    }
}

// ---------------- F: epilogue (total/norm) @ out_proj + x ----------------
__global__ void kF(const float* __restrict__ x, const float* __restrict__ tp,
                   const float* __restrict__ op, float* __restrict__ out) {
    int r0 = blockIdx.x * ROWS;
    int t = threadIdx.x;
    __shared__ __align__(16) float ts[ROWS][DDIM];
    #pragma unroll
    for (int r = 0; r < ROWS; ++r) {
        int l = (r0 + r) & (LSEQ - 1);
        float invn = 1.0f / (2.0f * sqrtf((float)(l + 1)));
        ts[r][t] = tp[(size_t)(r0 + r) * DDIM + t] * invn;
    }
    __syncthreads();
    float a0 = 0.f, a1 = 0.f;
    const float4* t40 = (const float4*)&ts[0][0];
    const float4* t41 = (const float4*)&ts[1][0];
    #pragma unroll 4
    for (int i4 = 0; i4 < DDIM / 4; ++i4) {
        float4 v0 = t40[i4], v1 = t41[i4];
        float w0 = op[(4*i4+0) * DDIM + t];
        float w1 = op[(4*i4+1) * DDIM + t];
        float w2 = op[(4*i4+2) * DDIM + t];
        float w3 = op[(4*i4+3) * DDIM + t];
        a0 += v0.x * w0 + v0.y * w1 + v0.z * w2 + v0.w * w3;
        a1 += v1.x * w0 + v1.y * w1 + v1.z * w2 + v1.w * w3;
    }
    out[(size_t)(r0 + 0) * DDIM + t] = x[(size_t)(r0 + 0) * DDIM + t] + a0;
    out[(size_t)(r0 + 1) * DDIM + t] = x[(size_t)(r0 + 1) * DDIM + t] + a1;
}

extern "C" void kernel_launch(void* const* d_in, const int* in_sizes, int n_in,
                              void* d_out, int out_size, void* d_ws, size_t ws_size,
                              hipStream_t stream) {
    const float* x   = (const float*)d_in[0];
    const float* kp  = (const float*)d_in[1];
    const float* qp  = (const float*)d_in[2];
    const float* vp  = (const float*)d_in[3];
    const float* op  = (const float*)d_in[4];
    const float* lkp = (const float*)d_in[5];
    const float* pf  = (const float*)d_in[7];
    const float* bre = (const float*)d_in[10];
    const float* bim = (const float*)d_in[11];
    float* out = (float*)d_out;

    const int B = 2;
    float* w = (float*)d_ws;
    size_t off = 0;
    float* coef  = w + off; off += (size_t)B * LSEQ * CSTR;       // 294912
    float* V     = w + off; off += (size_t)B * LSEQ * DDIM;       // 524288
    float* pers  = w + off; off += (size_t)B * LSEQ * DDIM;       // aliased as tp
    float* chp   = w + off; off += (size_t)B * 8 * LSEQ;          // 16384
    float* Ssum  = w + off; off += (size_t)B * NCS * DDIM;
    float* Ssq   = w + off; off += (size_t)B * NCS * DDIM;
    float* rmean = w + off; off += (size_t)B * LSEQ * DDIM;
    float* rstd  = w + off; off += (size_t)B * LSEQ * DDIM;
    float* S     = w + off; off += (size_t)B * NC * 72 * DDIM;    // 2359296
    // total ~19.1 MB

    kA<<<dim3(1024 + 32),  dim3(256), 0, stream>>>(x, kp, qp, vp, pf, coef, V, Ssum, Ssq);
    kB<<<dim3(16 + 32),    dim3(256), 0, stream>>>(x, coef, chp, Ssum, Ssq, rmean, rstd);
    kC<<<dim3(1024 + 128), dim3(256), 0, stream>>>(x, rmean, rstd, lkp, bre, bim, pers,
                                                   coef, V, chp, S);
    kD<<<dim3(144),        dim3(256), 0, stream>>>(S);
    kE<<<dim3(128),        dim3(256), 0, stream>>>(coef, V, chp, S, pers);
    kF<<<dim3(1024),       dim3(256), 0, stream>>>(x, pers, op, out);
}